// Round 14
// baseline (1793.206 us; speedup 1.0000x reference)
//
#include <hip/hip_runtime.h>
#include <hip/hip_fp16.h>

#define BBATCH 4
#define CCH 72
#define HROW 256
#define WCOL 256
#define HWSZ (HROW*WCOL)
#define NPC (BBATCH*HROW*WCOL)
#define BNEPS 1e-3f
#define NSH 64        // stats shards (R5: fixes same-address atomic serialization)
#define SST 144       // floats per shard: [0..71]=sum, [72..143]=sumsq

typedef unsigned short u16;
typedef unsigned int u32;
typedef _Float16 h8 __attribute__((ext_vector_type(8)));
typedef float f32x4 __attribute__((ext_vector_type(4)));

__device__ __forceinline__ float h2f(u16 h_){ return __half2float(__ushort_as_half(h_)); }
__device__ __forceinline__ u16 f2h(float f){ return __half_as_ushort(__float2half(f)); }
__device__ __forceinline__ u32 pack2(float a, float b){ return (u32)f2h(a) | ((u32)f2h(b)<<16); }
__device__ __forceinline__ float clip8(float v){ return fminf(fmaxf(v,-8.f),8.f); }

// BN-train scale/shift from sharded sum/sumsq (wave-parallel butterfly). c wave-uniform.
__device__ __forceinline__ void get_ss_wave(int c, int lane, const float* __restrict__ pstat,
                                            const float* __restrict__ gam, const float* __restrict__ bet,
                                            float& sc, float& sh){
  float s = pstat[lane*SST + c];
  float q = pstat[lane*SST + 72 + c];
  #pragma unroll
  for (int off=32; off; off>>=1){ s += __shfl_xor(s,off); q += __shfl_xor(q,off); }
  float mean = s * (1.0f/(float)NPC);
  float var  = q * (1.0f/(float)NPC) - mean*mean;
  sc = gam[c] * rsqrtf(var + BNEPS);
  sh = bet[c] - mean*sc;
}

// Last-block finalize: wave(s) butterfly-reduce all 64 shards for a channel range and
// write fss = [sc[72], sh[72]]. Deterministic: same sums in same order regardless of
// which block runs it.
__device__ __forceinline__ void finalize_ss(int c, int lane, const float* __restrict__ shards,
                                            const float* __restrict__ gam, const float* __restrict__ bet,
                                            float* __restrict__ fss){
  float s = __hip_atomic_load(&shards[lane*SST + c],      __ATOMIC_RELAXED, __HIP_MEMORY_SCOPE_AGENT);
  float q = __hip_atomic_load(&shards[lane*SST + 72 + c], __ATOMIC_RELAXED, __HIP_MEMORY_SCOPE_AGENT);
  #pragma unroll
  for (int off=32; off; off>>=1){ s += __shfl_xor(s,off); q += __shfl_xor(q,off); }
  if (lane == 0){
    float mean = s * (1.0f/(float)NPC);
    float var  = q * (1.0f/(float)NPC) - mean*mean;
    float scv  = gam[c] * rsqrtf(var + BNEPS);
    fss[c]      = scv;
    fss[72 + c] = bet[c] - mean*scv;
  }
}

// ---------------- Weight prep: all pw weights -> padded fp16 [slab][80][40] ----------------
__global__ __launch_bounds__(256) void k_prep(const float* __restrict__ ew,
    const float* __restrict__ pwall, u16* __restrict__ Wp)
{
  for (int e = blockIdx.x*256 + threadIdx.x; e < 14*3200; e += gridDim.x*256){
    int slab = e / 3200, rem = e - slab*3200;
    int row = rem / 40, col = rem - row*40;
    float w = 0.f;
    if (slab < 2){
      int c = slab*32 + col;
      if (row < 72 && col < 32 && c < 36) w = ew[row*36 + c];
    } else {
      int u = (slab-2)/3, kb = (slab-2)%3;
      int c = kb*32 + col;
      if (row < 72 && col < 32) w = pwall[u*5184 + row*72 + c];
    }
    Wp[e] = f2h(w);
  }
}

// ---------------- Pointwise conv (CIN -> 72) via MFMA 16x16x32_f16, zero-staging (R12 form) ----
// R14: input BN scale/shift read from finalized fss (2 floats/ch) instead of re-reducing
// 64 shards (36KB + serial chain) per block. Output stats finalized by the LAST block.
template<int CIN, int RAW>
__global__ __launch_bounds__(512) void k_pw(const void* __restrict__ in_,
    u16* __restrict__ out, const u16* __restrict__ Wp,
    const float* __restrict__ fss_in,
    float* __restrict__ ostat, float* __restrict__ fss_out,
    const float* __restrict__ gam_o, const float* __restrict__ bet_o,
    int* __restrict__ ctr, int nblk)
{
  constexpr int KB = (CIN + 31) / 32;    // K-steps of 32
  __shared__ __align__(16) u16 xs[72*264];   // epilogue bounce (38KB)
  __shared__ float tsc[80], tsh[80];
  __shared__ float sst[72], sqt[72];
  __shared__ int lastf;

  const int tid  = threadIdx.x;
  const int lane = tid & 63;
  const int wid  = tid >> 6;             // wave 0..7 -> px columns wid*32 .. wid*32+31
  const int g    = lane >> 4;            // k-octet group
  const int li   = lane & 15;
  const int b    = blockIdx.x >> 8;
  const int hrow = blockIdx.x & 255;

  if (tid < 72){ sst[tid] = 0.f; sqt[tid] = 0.f; }

  if constexpr (!RAW){
    if (tid < 72){ tsc[tid] = fss_in[tid]; tsh[tid] = fss_in[72 + tid]; }
    __syncthreads();
  }

  // ---- MFMA loop: B-fragments direct from global, BN+clip in-register, no barriers ----
  const size_t base_in = (size_t)b*CIN*HWSZ + (size_t)hrow*WCOL;
  const int px0 = wid*32 + li;           // bf0 pixel; bf1 = px0+16 (same 64B line)
  f32x4 acc[5][2];
  #pragma unroll
  for (int mt=0; mt<5; ++mt){ acc[mt][0] = (f32x4){0,0,0,0}; acc[mt][1] = (f32x4){0,0,0,0}; }

  #pragma unroll
  for (int kb2 = 0; kb2 < KB; ++kb2){
    h8 bf0, bf1;
    #pragma unroll
    for (int j = 0; j < 8; ++j){
      int c  = kb2*32 + g*8 + j;
      int cc = (c < CIN) ? c : 0;        // clamp addr; value zeroed below (NaN-safe)
      float v0, v1;
      if constexpr (RAW){
        const float* ip = (const float*)in_ + base_in + (size_t)cc*HWSZ;
        v0 = ip[px0]; v1 = ip[px0 + 16];
      } else {
        const u16* ip = (const u16*)in_ + base_in + (size_t)cc*HWSZ;
        float scv = tsc[cc], shv = tsh[cc];
        v0 = clip8(h2f(ip[px0])*scv + shv);
        v1 = clip8(h2f(ip[px0 + 16])*scv + shv);
      }
      bool ok = (c < CIN);
      bf0[j] = (_Float16)(ok ? v0 : 0.f);
      bf1[j] = (_Float16)(ok ? v1 : 0.f);
    }
    #pragma unroll
    for (int mt = 0; mt < 5; ++mt){
      h8 ah = *(const h8*)(Wp + (size_t)(kb2*80 + mt*16 + li)*40 + g*8);
      acc[mt][0] = __builtin_amdgcn_mfma_f32_16x16x32_f16(ah, bf0, acc[mt][0], 0, 0, 0);
      acc[mt][1] = __builtin_amdgcn_mfma_f32_16x16x32_f16(ah, bf1, acc[mt][1], 0, 0, 0);
    }
  }
  __syncthreads();   // sst/sqt init + (RAW) first barrier

  // ---- epilogue: acc -> LDS [72][264] (waves write disjoint px columns) ----
  #pragma unroll
  for (int mt = 0; mt < 5; ++mt){
    int o = mt*16 + g*4;
    if (o < 72){
      #pragma unroll
      for (int t2 = 0; t2 < 2; ++t2){
        int px = wid*32 + t2*16 + li;
        #pragma unroll
        for (int r = 0; r < 4; ++r)
          xs[(o + r)*264 + px] = f2h(acc[mt][t2][r]);
      }
    }
  }
  __syncthreads();

  // ---- readback: coalesced uint4 stores + fused stats ----
  #pragma unroll
  for (int it = 0; it < 5; ++it){
    int e = tid + it*512;
    if (e < 72*32){
      int o = e >> 5, m = e & 31;
      uint4 v = *(const uint4*)&xs[o*264 + m*8];
      u32 rr[4] = {v.x, v.y, v.z, v.w};
      float s = 0.f, q = 0.f;
      #pragma unroll
      for (int q2=0; q2<4; ++q2){
        float a  = h2f((u16)rr[q2]);
        float bq = h2f((u16)(rr[q2]>>16));
        s += a + bq;
        q = fmaf(a,a,q); q = fmaf(bq,bq,q);
      }
      *(uint4*)(out + (size_t)b*CCH*HWSZ + (size_t)o*HWSZ + (size_t)hrow*WCOL + m*8) = v;
      #pragma unroll
      for (int off = 1; off <= 16; off <<= 1){ s += __shfl_xor(s, off); q += __shfl_xor(q, off); }
      if ((lane & 31) == 0){ atomicAdd(&sst[o], s); atomicAdd(&sqt[o], q); }
    }
  }
  __syncthreads();
  float* oshard = ostat + (size_t)(blockIdx.x & (NSH-1))*SST;
  if (tid < 72){
    atomicAdd(oshard + tid,      sst[tid]);
    atomicAdd(oshard + 72 + tid, sqt[tid]);
    __threadfence();
  }
  __syncthreads();
  if (tid == 0){
    lastf = (atomicAdd(ctr, 1) == nblk - 1);
  }
  __syncthreads();
  if (lastf){
    // 8 waves x 9 channels: butterfly-reduce shards -> fss_out
    #pragma unroll
    for (int i = 0; i < 9; ++i)
      finalize_ss(wid*9 + i, lane, ostat, gam_o, bet_o, fss_out);
  }
}

// ---------------- IIR scan along H (R12: W-split x4, 1-wave blocks, 2-deep pipeline) ----
// R14: input BN from fss (2 scalar loads). MODE 0: plain. MODE 2: h1 = relu(BN(in)) +
// relu(BN2(in2=y0)), stored to h1buf. Output stats stay sharded (dw consumes via butterfly).
template<int MODE>
__global__ __launch_bounds__(64) void k_iir(const u16* __restrict__ in, u16* __restrict__ out,
    const float* __restrict__ wabc, u16* __restrict__ h1buf, const u16* __restrict__ in2,
    const float* __restrict__ fss1, const float* __restrict__ fss2,
    float* __restrict__ ostat)
{
  const int tid = threadIdx.x;           // 0..63
  const int wq  = blockIdx.x & 3;        // W-quarter
  const int bc  = blockIdx.x >> 2;       // b*CCH + c
  const int c   = bc % CCH;
  const float sc = fss1[c], sh = fss1[72 + c];
  float sc2 = 0.f, sh2 = 0.f;
  if (MODE==2){ sc2 = fss2[c]; sh2 = fss2[72 + c]; }
  const float ka = wabc[c], kb = wabc[CCH+c], kcc = wabc[2*CCH+c];
  const size_t base = (size_t)bc*HWSZ + wq*64 + tid;
  float xprev=0.f, yprev=0.f, lsum=0.f, lssq=0.f;

  float a0[16], a1[16], r0[16], r1[16];

  auto LOADC = [&](int hb, float* xv, float* rv){
    #pragma unroll
    for (int j=0;j<16;++j){
      size_t idx = base + (size_t)(hb+j)*WCOL;
      xv[j] = h2f(in[idx]);
      if (MODE==2) rv[j] = h2f(in2[idx]);
    }
  };
  auto COMPC = [&](int hb, const float* xv, const float* rv){
    float x[16];
    #pragma unroll
    for (int j=0;j<16;++j){
      float v = fmaxf(xv[j]*sc + sh, 0.f);
      if (MODE==2){
        v += fmaxf(rv[j]*sc2 + sh2, 0.f);        // + h0 recomputed from y0
        h1buf[base + (size_t)(hb+j)*WCOL] = f2h(v);
      }
      x[j] = v;
    }
    if (hb == 0){ xprev = x[0]; yprev = x[0]; }  // y0 = (a+b+c)*x0
    float t[16];
    t[0] = fmaf(ka, x[0], kb*xprev);
    #pragma unroll
    for (int j=1;j<16;++j) t[j] = fmaf(ka, x[j], kb*x[j-1]);
    #pragma unroll
    for (int j=0;j<16;++j){
      yprev = fmaf(kcc, yprev, t[j]);            // 1-FMA dependent chain
      out[base + (size_t)(hb+j)*WCOL] = f2h(yprev);
      lsum += yprev; lssq = fmaf(yprev,yprev,lssq);
    }
    xprev = x[15];
  };

  LOADC(0, a0, r0);
  #pragma unroll
  for (int hb = 0; hb < HROW; hb += 32){
    LOADC(hb+16, a1, r1);
    COMPC(hb, a0, r0);
    if (hb+32 < HROW) LOADC(hb+32, a0, r0);
    COMPC(hb+16, a1, r1);
  }

  #pragma unroll
  for (int off=32; off; off>>=1){ lsum += __shfl_xor(lsum,off); lssq += __shfl_xor(lssq,off); }
  if (tid==0){
    float* oshard = ostat + (size_t)(blockIdx.x & (NSH-1))*SST;
    atomicAdd(oshard + c,      lsum);
    atomicAdd(oshard + 72 + c, lssq);
  }
}

// ---------------- Depthwise 5-tap along W, fused input BN+clip, fp16 IO (R12 form) ----------
// Consumer side: butterfly on iir shards (unchanged). R14: LAST block finalizes output
// stats into fss_out for the pw consumer.
__global__ __launch_bounds__(256) void k_dw(const u16* __restrict__ in, u16* __restrict__ out,
    const float* __restrict__ wgt,
    const float* __restrict__ pstat,
    const float* __restrict__ pgam, const float* __restrict__ pbet,
    float* __restrict__ ostat, float* __restrict__ fss_out,
    const float* __restrict__ gam_o, const float* __restrict__ bet_o,
    int* __restrict__ ctr, int nblk)
{
  __shared__ float xs[8*264];   // row stride 264, data at col 4+w, zero halo
  __shared__ float rs[4], rq[4];
  __shared__ int lastf;
  const int tid = threadIdx.x;
  const int ht = blockIdx.x & 31;
  const int bc = blockIdx.x >> 5;
  const int c = bc % CCH;
  float sc, sh; get_ss_wave(c, tid&63, pstat, pgam, pbet, sc, sh);
  const float w0=wgt[c*5+0], w1=wgt[c*5+1], w2=wgt[c*5+2], w3=wgt[c*5+3], w4=wgt[c*5+4];
  const size_t base = (size_t)bc*HWSZ + (size_t)ht*(8*WCOL);

  if (tid < 64){
    int r = tid>>3, k = tid&7;
    xs[r*264 + (k<4 ? k : 256+k)] = 0.f;
  }
  const int r = tid >> 5, m = tid & 31;
  {
    uint4 v = *(const uint4*)(in + base + (size_t)r*WCOL + m*8);
    u32 rr[4] = {v.x, v.y, v.z, v.w};
    float f[8];
    #pragma unroll
    for (int q=0;q<4;++q){
      f[2*q]   = clip8(h2f((u16)rr[q])*sc + sh);
      f[2*q+1] = clip8(h2f((u16)(rr[q]>>16))*sc + sh);
    }
    float4* dst = (float4*)&xs[r*264 + 4 + m*8];
    dst[0] = make_float4(f[0],f[1],f[2],f[3]);
    dst[1] = make_float4(f[4],f[5],f[6],f[7]);
  }
  __syncthreads();
  float lsum=0.f, lssq=0.f;
  {
    const float* row = &xs[r*264 + m*8];
    float4 a0 = *(const float4*)(row+0);
    float4 a1 = *(const float4*)(row+4);
    float4 a2 = *(const float4*)(row+8);
    float4 a3 = *(const float4*)(row+12);
    float v[16] = {a0.x,a0.y,a0.z,a0.w, a1.x,a1.y,a1.z,a1.w,
                   a2.x,a2.y,a2.z,a2.w, a3.x,a3.y,a3.z,a3.w};
    float o[8];
    #pragma unroll
    for (int j=0;j<8;++j){
      float y = w0*v[j+2];
      y = fmaf(w1, v[j+3], y);
      y = fmaf(w2, v[j+4], y);
      y = fmaf(w3, v[j+5], y);
      y = fmaf(w4, v[j+6], y);
      o[j] = y;
      lsum += y; lssq = fmaf(y,y,lssq);
    }
    *(uint4*)(out + base + (size_t)r*WCOL + m*8) =
        make_uint4(pack2(o[0],o[1]), pack2(o[2],o[3]), pack2(o[4],o[5]), pack2(o[6],o[7]));
  }
  #pragma unroll
  for (int off=32; off; off>>=1){ lsum += __shfl_xor(lsum,off); lssq += __shfl_xor(lssq,off); }
  if ((tid&63)==0){ rs[tid>>6]=lsum; rq[tid>>6]=lssq; }
  __syncthreads();
  if (tid==0){
    float* oshard = ostat + (size_t)(blockIdx.x & (NSH-1))*SST;
    atomicAdd(oshard + c,      rs[0]+rs[1]+rs[2]+rs[3]);
    atomicAdd(oshard + 72 + c, rq[0]+rq[1]+rq[2]+rq[3]);
    __threadfence();
  }
  __syncthreads();
  if (tid == 0){
    lastf = (atomicAdd(ctr, 1) == nblk - 1);
  }
  __syncthreads();
  if (lastf){
    // 4 waves x 18 channels
    int w = tid >> 6, l = tid & 63;
    #pragma unroll
    for (int i = 0; i < 18; ++i)
      finalize_ss(w*18 + i, l, ostat, gam_o, bet_o, fss_out);
  }
}

// ---------------- Final: out = h1 + relu(BN(y12)) (fp32 output) ----------------
__global__ __launch_bounds__(256) void k_final(const u16* __restrict__ y12, const u16* __restrict__ h1,
    float* __restrict__ outp, const float* __restrict__ fss12)
{
  __shared__ float tsc[CCH], tsh[CCH];
  if (threadIdx.x < CCH){
    tsc[threadIdx.x] = fss12[threadIdx.x];
    tsh[threadIdx.x] = fss12[72 + threadIdx.x];
  }
  __syncthreads();
  const size_t TOTALQ = (size_t)BBATCH*CCH*HWSZ/4;
  for (size_t q = (size_t)blockIdx.x*blockDim.x + threadIdx.x; q < TOTALQ;
       q += (size_t)gridDim.x*blockDim.x){
    int cch = (int)((q >> 14) % CCH);
    float sc = tsc[cch], sh = tsh[cch];
    uint2 a = *(const uint2*)(y12 + q*4);
    uint2 b = *(const uint2*)(h1 + q*4);
    float4 o;
    o.x = fmaxf(h2f((u16)a.x)*sc+sh, 0.f)       + h2f((u16)b.x);
    o.y = fmaxf(h2f((u16)(a.x>>16))*sc+sh, 0.f) + h2f((u16)(b.x>>16));
    o.z = fmaxf(h2f((u16)a.y)*sc+sh, 0.f)       + h2f((u16)b.y);
    o.w = fmaxf(h2f((u16)(a.y>>16))*sc+sh, 0.f) + h2f((u16)(b.y>>16));
    *(float4*)(outp + q*4) = o;
  }
}

extern "C" void kernel_launch(void* const* d_in, const int* in_sizes, int n_in,
                              void* d_out, int out_size, void* d_ws, size_t ws_size,
                              hipStream_t stream)
{
  (void)in_sizes; (void)n_in; (void)out_size;
  const float* x   = (const float*)d_in[0];
  const float* ew  = (const float*)d_in[1];
  const float* eg  = (const float*)d_in[3];
  const float* ebt = (const float*)d_in[4];
  const float* iw  = (const float*)d_in[5];
  const float* ig  = (const float*)d_in[6];
  const float* ibt = (const float*)d_in[7];
  const float* dwt = (const float*)d_in[8];
  const float* dg  = (const float*)d_in[10];
  const float* dbt = (const float*)d_in[11];
  const float* pw  = (const float*)d_in[12];
  const float* pg  = (const float*)d_in[14];
  const float* pbt = (const float*)d_in[15];
  float* outp = (float*)d_out;

  const size_t BUFE = (size_t)BBATCH*CCH*HWSZ;       // 18,874,368 elements
  const size_t BUFB = BUFE*2;                        // fp16: 37.75 MB per buffer
  const size_t SHARDSB = (size_t)13*NSH*SST*sizeof(float);   // ~479 KB
  const size_t FSSB    = (size_t)13*144*sizeof(float);       // finalized sc/sh
  const size_t CTRB    = 64*sizeof(int);
  const size_t STATSB  = SHARDSB + FSSB + CTRB;
  const size_t WPB = (size_t)14*3200*sizeof(u16);    // 89.6 KB prepped weights
  char* ws = (char*)d_ws;
  // A holds y0 for the whole pipeline (unit-2 IIR recomputes h0 from it).
  u16* A = (u16*)ws;
  u16* C = (u16*)(ws + BUFB);
  u16* H = (u16*)(ws + 2*BUFB);                      // h1 buffer
  float* stats = (float*)(ws + 3*BUFB);
  float* fss   = (float*)((char*)stats + SHARDSB);
  int*   ctrs  = (int*)((char*)fss + FSSB);
  u16* Wp = (u16*)((char*)stats + ((STATSB+255)&~(size_t)255));
  u16* B;
  if (ws_size >= 4*BUFB + STATSB + WPB + 1024){
    B = (u16*)((char*)Wp + ((WPB+255)&~(size_t)255));
  } else {
    // B lives in d_out (dead before k_final, which reads C and H only)
    B = (u16*)d_out;
  }
  #define ST(s) (stats + (size_t)(s)*NSH*SST)
  #define FS(s) (fss + (size_t)(s)*144)
  #define WSLAB(u) (Wp + (size_t)(2 + 3*(u))*3200)

  hipMemsetAsync(stats, 0, STATSB, stream);

  dim3 blk(256);
  dim3 blkpw(512);
  dim3 blkiir(64);
  const int GPW  = BBATCH*HROW;     // 1024
  const int GIIR = BBATCH*CCH*4;    // 1152 (W-split x4)
  const int GDW  = BBATCH*CCH*32;   // 9216 (8 rows/block)
  k_prep<<<18, blk, 0, stream>>>(ew, pw, Wp);
  // s0: expand pointwise (fp32 x -> y0 in A); finalize fss0 with (eg,ebt)
  k_pw<36,1><<<GPW, blkpw, 0, stream>>>((const void*)x, A, Wp,
      nullptr, ST(0), FS(0), eg, ebt, ctrs+0, GPW);
  // unit 0  (A preserved as y0)
  k_iir<0><<<GIIR, blkiir, 0, stream>>>(A, B, iw+0, nullptr, nullptr, FS(0), nullptr, ST(1));
  k_dw    <<<GDW, blk, 0, stream>>>(B, C, dwt+0, ST(1), ig+0, ibt+0,
      ST(2), FS(2), dg+0, dbt+0, ctrs+2, GDW);
  k_pw<72,0><<<GPW, blkpw, 0, stream>>>(C, B, WSLAB(0),
      FS(2), ST(3), FS(3), pg+0, pbt+0, ctrs+3, GPW);
  // unit 1
  k_iir<0><<<GIIR, blkiir, 0, stream>>>(B, C, iw+216, nullptr, nullptr, FS(3), nullptr, ST(4));
  k_dw    <<<GDW, blk, 0, stream>>>(C, B, dwt+360, ST(4), ig+72, ibt+72,
      ST(5), FS(5), dg+72, dbt+72, ctrs+5, GDW);
  k_pw<72,0><<<GPW, blkpw, 0, stream>>>(B, C, WSLAB(1),
      FS(5), ST(6), FS(6), pg+72, pbt+72, ctrs+6, GPW);
  // unit 2: h1 = relu(BN6(y6=C)) + relu(BN0(y0=A)) -> H; IIR(h1) -> B
  k_iir<2><<<GIIR, blkiir, 0, stream>>>(C, B, iw+432, H, A, FS(6), FS(0), ST(7));
  k_dw    <<<GDW, blk, 0, stream>>>(B, C, dwt+720, ST(7), ig+144, ibt+144,
      ST(8), FS(8), dg+144, dbt+144, ctrs+8, GDW);
  k_pw<72,0><<<GPW, blkpw, 0, stream>>>(C, B, WSLAB(2),
      FS(8), ST(9), FS(9), pg+144, pbt+144, ctrs+9, GPW);
  // unit 3
  k_iir<0><<<GIIR, blkiir, 0, stream>>>(B, C, iw+648, nullptr, nullptr, FS(9), nullptr, ST(10));
  k_dw    <<<GDW, blk, 0, stream>>>(C, B, dwt+1080, ST(10), ig+216, ibt+216,
      ST(11), FS(11), dg+216, dbt+216, ctrs+11, GDW);
  k_pw<72,0><<<GPW, blkpw, 0, stream>>>(B, C, WSLAB(3),
      FS(11), ST(12), FS(12), pg+216, pbt+216, ctrs+12, GPW);
  // out = h1 + relu(BN12(y12))
  k_final<<<2048, blk, 0, stream>>>(C, H, outp, FS(12));
  #undef ST
  #undef FS
  #undef WSLAB
}

// Round 15
// 321.411 us; speedup vs baseline: 5.5792x; 5.5792x over previous
//
#include <hip/hip_runtime.h>
#include <hip/hip_fp16.h>

#define BBATCH 4
#define CCH 72
#define HROW 256
#define WCOL 256
#define HWSZ (HROW*WCOL)
#define NPC (BBATCH*HROW*WCOL)
#define BNEPS 1e-3f
#define NSH 64        // stats shards (R5: fixes same-address atomic serialization)
#define SST 144       // floats per shard: [0..71]=sum, [72..143]=sumsq

typedef unsigned short u16;
typedef unsigned int u32;
typedef _Float16 h8 __attribute__((ext_vector_type(8)));
typedef float f32x4 __attribute__((ext_vector_type(4)));

__device__ __forceinline__ float h2f(u16 h_){ return __half2float(__ushort_as_half(h_)); }
__device__ __forceinline__ u16 f2h(float f){ return __half_as_ushort(__float2half(f)); }
__device__ __forceinline__ u32 pack2(float a, float b){ return (u32)f2h(a) | ((u32)f2h(b)<<16); }
__device__ __forceinline__ float clip8(float v){ return fminf(fmaxf(v,-8.f),8.f); }

// BN-train scale/shift from sharded sum/sumsq (wave-parallel butterfly). c wave-uniform.
// R14 lesson: do NOT replace these consumer-side butterflies with a last-block-finalize —
// the last-block atomic counter is a same-address RMW serial chain (9216 blocks -> 318us).
__device__ __forceinline__ void get_ss_wave(int c, int lane, const float* __restrict__ pstat,
                                            const float* __restrict__ gam, const float* __restrict__ bet,
                                            float& sc, float& sh){
  float s = pstat[lane*SST + c];
  float q = pstat[lane*SST + 72 + c];
  #pragma unroll
  for (int off=32; off; off>>=1){ s += __shfl_xor(s,off); q += __shfl_xor(q,off); }
  float mean = s * (1.0f/(float)NPC);
  float var  = q * (1.0f/(float)NPC) - mean*mean;
  sc = gam[c] * rsqrtf(var + BNEPS);
  sh = bet[c] - mean*sc;
}

// ---------------- Weight prep: all pw weights -> padded fp16 [slab][80][40] ----------------
__global__ __launch_bounds__(256) void k_prep(const float* __restrict__ ew,
    const float* __restrict__ pwall, u16* __restrict__ Wp)
{
  for (int e = blockIdx.x*256 + threadIdx.x; e < 14*3200; e += gridDim.x*256){
    int slab = e / 3200, rem = e - slab*3200;
    int row = rem / 40, col = rem - row*40;
    float w = 0.f;
    if (slab < 2){
      int c = slab*32 + col;
      if (row < 72 && col < 32 && c < 36) w = ew[row*36 + c];
    } else {
      int u = (slab-2)/3, kb = (slab-2)%3;
      int c = kb*32 + col;
      if (row < 72 && col < 32) w = pwall[u*5184 + row*72 + c];
    }
    Wp[e] = f2h(w);
  }
}

// ---------------- Pointwise conv (CIN -> 72) via MFMA 16x16x32_f16, zero-staging (R11) ----------
template<int CIN, int RAW>
__global__ __launch_bounds__(512) void k_pw(const void* __restrict__ in_,
    u16* __restrict__ out, const u16* __restrict__ Wp,
    const float* __restrict__ pstat,
    const float* __restrict__ pgam, const float* __restrict__ pbet,
    float* __restrict__ ostat)
{
  constexpr int KB = (CIN + 31) / 32;    // K-steps of 32
  __shared__ __align__(16) u16 xs[72*264];   // epilogue bounce (38KB); head = BN scratch overlay
  __shared__ float tsc[80], tsh[80];
  __shared__ float sst[72], sqt[72];
  float* pp4 = (float*)xs;               // [4][80] shard partials (dead before epilogue)
  float* pq4 = pp4 + 320;

  const int tid  = threadIdx.x;
  const int lane = tid & 63;
  const int wid  = tid >> 6;             // wave 0..7 -> px columns wid*32 .. wid*32+31
  const int g    = lane >> 4;            // k-octet group
  const int li   = lane & 15;
  const int b    = blockIdx.x >> 8;
  const int hrow = blockIdx.x & 255;

  if (tid < 72){ sst[tid] = 0.f; sqt[tid] = 0.f; }

  // ---- BN scale/shift of the input (4-group parallel shard sum in overlaid LDS) ----
  if constexpr (!RAW){
    int sg = tid >> 7, c = tid & 127;
    if (c < 72){
      float s = 0.f, q = 0.f;
      #pragma unroll
      for (int k2 = 0; k2 < 16; ++k2){
        s += pstat[(sg*16 + k2)*SST + c];
        q += pstat[(sg*16 + k2)*SST + 72 + c];
      }
      pp4[sg*80 + c] = s; pq4[sg*80 + c] = q;
    }
    __syncthreads();
    if (tid < CIN){
      float s = pp4[tid] + pp4[80+tid] + pp4[160+tid] + pp4[240+tid];
      float q = pq4[tid] + pq4[80+tid] + pq4[160+tid] + pq4[240+tid];
      float mean = s * (1.0f/(float)NPC);
      float var  = q * (1.0f/(float)NPC) - mean*mean;
      float scv  = pgam[tid] * rsqrtf(var + BNEPS);
      tsc[tid] = scv;
      tsh[tid] = pbet[tid] - mean*scv;
    }
    __syncthreads();   // tsc/tsh ready; pp4/pq4 (xs head) now dead -> epilogue may reuse
  }

  // ---- MFMA loop: B-fragments direct from global, BN+clip in-register, no barriers ----
  const size_t base_in = (size_t)b*CIN*HWSZ + (size_t)hrow*WCOL;
  const int px0 = wid*32 + li;           // bf0 pixel; bf1 = px0+16 (same 64B line)
  f32x4 acc[5][2];
  #pragma unroll
  for (int mt=0; mt<5; ++mt){ acc[mt][0] = (f32x4){0,0,0,0}; acc[mt][1] = (f32x4){0,0,0,0}; }

  #pragma unroll
  for (int kb2 = 0; kb2 < KB; ++kb2){
    h8 bf0, bf1;
    #pragma unroll
    for (int j = 0; j < 8; ++j){
      int c  = kb2*32 + g*8 + j;
      int cc = (c < CIN) ? c : 0;        // clamp addr; value zeroed below (NaN-safe)
      float v0, v1;
      if constexpr (RAW){
        const float* ip = (const float*)in_ + base_in + (size_t)cc*HWSZ;
        v0 = ip[px0]; v1 = ip[px0 + 16];
      } else {
        const u16* ip = (const u16*)in_ + base_in + (size_t)cc*HWSZ;
        float scv = tsc[cc], shv = tsh[cc];
        v0 = clip8(h2f(ip[px0])*scv + shv);
        v1 = clip8(h2f(ip[px0 + 16])*scv + shv);
      }
      bool ok = (c < CIN);
      bf0[j] = (_Float16)(ok ? v0 : 0.f);
      bf1[j] = (_Float16)(ok ? v1 : 0.f);
    }
    #pragma unroll
    for (int mt = 0; mt < 5; ++mt){
      h8 ah = *(const h8*)(Wp + (size_t)(kb2*80 + mt*16 + li)*40 + g*8);
      acc[mt][0] = __builtin_amdgcn_mfma_f32_16x16x32_f16(ah, bf0, acc[mt][0], 0, 0, 0);
      acc[mt][1] = __builtin_amdgcn_mfma_f32_16x16x32_f16(ah, bf1, acc[mt][1], 0, 0, 0);
    }
  }

  // ---- epilogue: acc -> LDS [72][264] (waves write disjoint px columns) ----
  #pragma unroll
  for (int mt = 0; mt < 5; ++mt){
    int o = mt*16 + g*4;
    if (o < 72){
      #pragma unroll
      for (int t2 = 0; t2 < 2; ++t2){
        int px = wid*32 + t2*16 + li;
        #pragma unroll
        for (int r = 0; r < 4; ++r)
          xs[(o + r)*264 + px] = f2h(acc[mt][t2][r]);
      }
    }
  }
  __syncthreads();

  // ---- readback: coalesced uint4 stores + fused stats ----
  #pragma unroll
  for (int it = 0; it < 5; ++it){
    int e = tid + it*512;
    if (e < 72*32){
      int o = e >> 5, m = e & 31;
      uint4 v = *(const uint4*)&xs[o*264 + m*8];
      u32 rr[4] = {v.x, v.y, v.z, v.w};
      float s = 0.f, q = 0.f;
      #pragma unroll
      for (int q2=0; q2<4; ++q2){
        float a  = h2f((u16)rr[q2]);
        float bq = h2f((u16)(rr[q2]>>16));
        s += a + bq;
        q = fmaf(a,a,q); q = fmaf(bq,bq,q);
      }
      *(uint4*)(out + (size_t)b*CCH*HWSZ + (size_t)o*HWSZ + (size_t)hrow*WCOL + m*8) = v;
      #pragma unroll
      for (int off = 1; off <= 16; off <<= 1){ s += __shfl_xor(s, off); q += __shfl_xor(q, off); }
      if ((lane & 31) == 0){ atomicAdd(&sst[o], s); atomicAdd(&sqt[o], q); }
    }
  }
  __syncthreads();
  if (tid < 72){
    float* oshard = ostat + (size_t)(blockIdx.x & (NSH-1))*SST;
    atomicAdd(oshard + tid,      sst[tid]);
    atomicAdd(oshard + 72 + tid, sqt[tid]);
  }
}

// ---------------- IIR scan along H (R12: W-split x4, 1-wave blocks, 2-deep pipeline) ----
// MODE 0: plain. MODE 2: h1 = relu(BN(in)) + relu(BN2(in2=y0)), stored to h1buf.
template<int MODE>
__global__ __launch_bounds__(64) void k_iir(const u16* __restrict__ in, u16* __restrict__ out,
    const float* __restrict__ wabc, u16* __restrict__ h1buf, const u16* __restrict__ in2,
    const float* __restrict__ pstat, const float* __restrict__ pgam, const float* __restrict__ pbet,
    const float* __restrict__ pstat2, const float* __restrict__ pgam2, const float* __restrict__ pbet2,
    float* __restrict__ ostat)
{
  const int tid = threadIdx.x;           // 0..63
  const int wq  = blockIdx.x & 3;        // W-quarter
  const int bc  = blockIdx.x >> 2;       // b*CCH + c
  const int c   = bc % CCH;
  float sc, sh; get_ss_wave(c, tid, pstat, pgam, pbet, sc, sh);
  float sc2 = 0.f, sh2 = 0.f;
  if (MODE==2) get_ss_wave(c, tid, pstat2, pgam2, pbet2, sc2, sh2);
  const float ka = wabc[c], kb = wabc[CCH+c], kcc = wabc[2*CCH+c];
  const size_t base = (size_t)bc*HWSZ + wq*64 + tid;
  float xprev=0.f, yprev=0.f, lsum=0.f, lssq=0.f;

  float a0[16], a1[16], r0[16], r1[16];

  auto LOADC = [&](int hb, float* xv, float* rv){
    #pragma unroll
    for (int j=0;j<16;++j){
      size_t idx = base + (size_t)(hb+j)*WCOL;
      xv[j] = h2f(in[idx]);
      if (MODE==2) rv[j] = h2f(in2[idx]);
    }
  };
  auto COMPC = [&](int hb, const float* xv, const float* rv){
    float x[16];
    #pragma unroll
    for (int j=0;j<16;++j){
      float v = fmaxf(xv[j]*sc + sh, 0.f);
      if (MODE==2){
        v += fmaxf(rv[j]*sc2 + sh2, 0.f);        // + h0 recomputed from y0
        h1buf[base + (size_t)(hb+j)*WCOL] = f2h(v);
      }
      x[j] = v;
    }
    if (hb == 0){ xprev = x[0]; yprev = x[0]; }  // y0 = (a+b+c)*x0
    float t[16];
    t[0] = fmaf(ka, x[0], kb*xprev);
    #pragma unroll
    for (int j=1;j<16;++j) t[j] = fmaf(ka, x[j], kb*x[j-1]);
    #pragma unroll
    for (int j=0;j<16;++j){
      yprev = fmaf(kcc, yprev, t[j]);            // 1-FMA dependent chain
      out[base + (size_t)(hb+j)*WCOL] = f2h(yprev);
      lsum += yprev; lssq = fmaf(yprev,yprev,lssq);
    }
    xprev = x[15];
  };

  LOADC(0, a0, r0);
  #pragma unroll
  for (int hb = 0; hb < HROW; hb += 32){
    LOADC(hb+16, a1, r1);
    COMPC(hb, a0, r0);
    if (hb+32 < HROW) LOADC(hb+32, a0, r0);
    COMPC(hb+16, a1, r1);
  }

  #pragma unroll
  for (int off=32; off; off>>=1){ lsum += __shfl_xor(lsum,off); lssq += __shfl_xor(lssq,off); }
  if (tid==0){
    float* oshard = ostat + (size_t)(blockIdx.x & (NSH-1))*SST;
    atomicAdd(oshard + c,      lsum);
    atomicAdd(oshard + 72 + c, lssq);
  }
}

// ---------------- Depthwise 5-tap along W, fused input BN+clip, fp16 IO ----------
__global__ __launch_bounds__(256) void k_dw(const u16* __restrict__ in, u16* __restrict__ out,
    const float* __restrict__ wgt,
    const float* __restrict__ pstat,
    const float* __restrict__ pgam, const float* __restrict__ pbet,
    float* __restrict__ ostat)
{
  __shared__ float xs[8*264];   // row stride 264, data at col 4+w, zero halo
  __shared__ float rs[4], rq[4];
  const int tid = threadIdx.x;
  const int ht = blockIdx.x & 31;
  const int bc = blockIdx.x >> 5;
  const int c = bc % CCH;
  float sc, sh; get_ss_wave(c, tid&63, pstat, pgam, pbet, sc, sh);
  const float w0=wgt[c*5+0], w1=wgt[c*5+1], w2=wgt[c*5+2], w3=wgt[c*5+3], w4=wgt[c*5+4];
  const size_t base = (size_t)bc*HWSZ + (size_t)ht*(8*WCOL);

  if (tid < 64){
    int r = tid>>3, k = tid&7;
    xs[r*264 + (k<4 ? k : 256+k)] = 0.f;
  }
  const int r = tid >> 5, m = tid & 31;
  {
    uint4 v = *(const uint4*)(in + base + (size_t)r*WCOL + m*8);
    u32 rr[4] = {v.x, v.y, v.z, v.w};
    float f[8];
    #pragma unroll
    for (int q=0;q<4;++q){
      f[2*q]   = clip8(h2f((u16)rr[q])*sc + sh);
      f[2*q+1] = clip8(h2f((u16)(rr[q]>>16))*sc + sh);
    }
    float4* dst = (float4*)&xs[r*264 + 4 + m*8];
    dst[0] = make_float4(f[0],f[1],f[2],f[3]);
    dst[1] = make_float4(f[4],f[5],f[6],f[7]);
  }
  __syncthreads();
  float lsum=0.f, lssq=0.f;
  {
    const float* row = &xs[r*264 + m*8];
    float4 a0 = *(const float4*)(row+0);
    float4 a1 = *(const float4*)(row+4);
    float4 a2 = *(const float4*)(row+8);
    float4 a3 = *(const float4*)(row+12);
    float v[16] = {a0.x,a0.y,a0.z,a0.w, a1.x,a1.y,a1.z,a1.w,
                   a2.x,a2.y,a2.z,a2.w, a3.x,a3.y,a3.z,a3.w};
    float o[8];
    #pragma unroll
    for (int j=0;j<8;++j){
      float y = w0*v[j+2];
      y = fmaf(w1, v[j+3], y);
      y = fmaf(w2, v[j+4], y);
      y = fmaf(w3, v[j+5], y);
      y = fmaf(w4, v[j+6], y);
      o[j] = y;
      lsum += y; lssq = fmaf(y,y,lssq);
    }
    *(uint4*)(out + base + (size_t)r*WCOL + m*8) =
        make_uint4(pack2(o[0],o[1]), pack2(o[2],o[3]), pack2(o[4],o[5]), pack2(o[6],o[7]));
  }
  #pragma unroll
  for (int off=32; off; off>>=1){ lsum += __shfl_xor(lsum,off); lssq += __shfl_xor(lssq,off); }
  if ((tid&63)==0){ rs[tid>>6]=lsum; rq[tid>>6]=lssq; }
  __syncthreads();
  if (tid==0){
    float* oshard = ostat + (size_t)(blockIdx.x & (NSH-1))*SST;
    atomicAdd(oshard + c,      rs[0]+rs[1]+rs[2]+rs[3]);
    atomicAdd(oshard + 72 + c, rq[0]+rq[1]+rq[2]+rq[3]);
  }
}

// ---------------- Final: out = h1 + relu(BN(y12)) (fp32 output) ----------------
__global__ __launch_bounds__(256) void k_final(const u16* __restrict__ y12, const u16* __restrict__ h1,
    float* __restrict__ outp,
    const float* __restrict__ pstat,
    const float* __restrict__ pgam, const float* __restrict__ pbet)
{
  __shared__ float tsc[CCH], tsh[CCH];
  if (threadIdx.x < CCH){
    int cc = threadIdx.x;
    float s=0.f, q=0.f;
    for (int sh2=0; sh2<NSH; ++sh2){ s += pstat[sh2*SST + cc]; q += pstat[sh2*SST + 72 + cc]; }
    float mean = s * (1.0f/(float)NPC);
    float var  = q * (1.0f/(float)NPC) - mean*mean;
    float scv = pgam[cc] * rsqrtf(var + BNEPS);
    tsc[cc] = scv;
    tsh[cc] = pbet[cc] - mean*scv;
  }
  __syncthreads();
  const size_t TOTALQ = (size_t)BBATCH*CCH*HWSZ/4;
  for (size_t q = (size_t)blockIdx.x*blockDim.x + threadIdx.x; q < TOTALQ;
       q += (size_t)gridDim.x*blockDim.x){
    int cch = (int)((q >> 14) % CCH);
    float sc = tsc[cch], sh = tsh[cch];
    uint2 a = *(const uint2*)(y12 + q*4);
    uint2 b = *(const uint2*)(h1 + q*4);
    float4 o;
    o.x = fmaxf(h2f((u16)a.x)*sc+sh, 0.f)       + h2f((u16)b.x);
    o.y = fmaxf(h2f((u16)(a.x>>16))*sc+sh, 0.f) + h2f((u16)(b.x>>16));
    o.z = fmaxf(h2f((u16)a.y)*sc+sh, 0.f)       + h2f((u16)b.y);
    o.w = fmaxf(h2f((u16)(a.y>>16))*sc+sh, 0.f) + h2f((u16)(b.y>>16));
    *(float4*)(outp + q*4) = o;
  }
}

extern "C" void kernel_launch(void* const* d_in, const int* in_sizes, int n_in,
                              void* d_out, int out_size, void* d_ws, size_t ws_size,
                              hipStream_t stream)
{
  (void)in_sizes; (void)n_in; (void)out_size;
  const float* x   = (const float*)d_in[0];
  const float* ew  = (const float*)d_in[1];
  const float* eg  = (const float*)d_in[3];
  const float* ebt = (const float*)d_in[4];
  const float* iw  = (const float*)d_in[5];
  const float* ig  = (const float*)d_in[6];
  const float* ibt = (const float*)d_in[7];
  const float* dwt = (const float*)d_in[8];
  const float* dg  = (const float*)d_in[10];
  const float* dbt = (const float*)d_in[11];
  const float* pw  = (const float*)d_in[12];
  const float* pg  = (const float*)d_in[14];
  const float* pbt = (const float*)d_in[15];
  float* outp = (float*)d_out;

  const size_t BUFE = (size_t)BBATCH*CCH*HWSZ;     // 18,874,368 elements
  const size_t BUFB = BUFE*2;                      // fp16: 37.75 MB per buffer
  const size_t STATSB = (size_t)13*NSH*SST*sizeof(float);  // ~479 KB
  const size_t WPB = (size_t)14*3200*sizeof(u16);  // 89.6 KB prepped weights
  char* ws = (char*)d_ws;
  // A holds y0 for the whole pipeline (unit-2 IIR recomputes h0 from it).
  u16* A = (u16*)ws;
  u16* C = (u16*)(ws + BUFB);
  u16* H = (u16*)(ws + 2*BUFB);                    // h1 buffer
  float* stats = (float*)(ws + 3*BUFB);
  u16* Wp = (u16*)((char*)stats + STATSB);
  u16* B;
  if (ws_size >= 4*BUFB + STATSB + WPB + 256){
    B = (u16*)((char*)Wp + ((WPB+255)&~(size_t)255));
  } else {
    // B lives in d_out (dead before k_final, which reads C and H only)
    B = (u16*)d_out;
  }
  #define ST(s) (stats + (size_t)(s)*NSH*SST)
  #define WSLAB(u) (Wp + (size_t)(2 + 3*(u))*3200)

  hipMemsetAsync(stats, 0, STATSB, stream);

  dim3 blk(256);
  dim3 blkpw(512);
  dim3 blkiir(64);
  const int GIIR = BBATCH*CCH*4;   // W-split x4
  k_prep<<<18, blk, 0, stream>>>(ew, pw, Wp);
  // s0: expand pointwise (fp32 x -> y0 in A), raw stats0
  k_pw<36,1><<<BBATCH*HROW, blkpw, 0, stream>>>((const void*)x, A, Wp,
      nullptr, nullptr, nullptr, ST(0));
  // unit 0  (A preserved as y0)
  k_iir<0><<<GIIR, blkiir, 0, stream>>>(A, B, iw+0, nullptr, nullptr,
      ST(0), eg, ebt, nullptr, nullptr, nullptr, ST(1));
  k_dw    <<<BBATCH*CCH*32, blk, 0, stream>>>(B, C, dwt+0,    ST(1), ig+0,   ibt+0,   ST(2));
  k_pw<72,0><<<BBATCH*HROW, blkpw, 0, stream>>>(C, B, WSLAB(0), ST(2), dg+0,   dbt+0,   ST(3));
  // unit 1
  k_iir<0><<<GIIR, blkiir, 0, stream>>>(B, C, iw+216, nullptr, nullptr,
      ST(3), pg+0, pbt+0, nullptr, nullptr, nullptr, ST(4));
  k_dw    <<<BBATCH*CCH*32, blk, 0, stream>>>(C, B, dwt+360,  ST(4), ig+72,  ibt+72,  ST(5));
  k_pw<72,0><<<BBATCH*HROW, blkpw, 0, stream>>>(B, C, WSLAB(1), ST(5), dg+72,  dbt+72,  ST(6));
  // unit 2: h1 = relu(BN6(y6=C)) + relu(BN0(y0=A)) -> H; IIR(h1) -> B
  k_iir<2><<<GIIR, blkiir, 0, stream>>>(C, B, iw+432, H, A,
      ST(6), pg+72, pbt+72, ST(0), eg, ebt, ST(7));
  k_dw    <<<BBATCH*CCH*32, blk, 0, stream>>>(B, C, dwt+720,  ST(7), ig+144, ibt+144, ST(8));
  k_pw<72,0><<<BBATCH*HROW, blkpw, 0, stream>>>(C, B, WSLAB(2), ST(8), dg+144, dbt+144, ST(9));
  // unit 3
  k_iir<0><<<GIIR, blkiir, 0, stream>>>(B, C, iw+648, nullptr, nullptr,
      ST(9), pg+144, pbt+144, nullptr, nullptr, nullptr, ST(10));
  k_dw    <<<BBATCH*CCH*32, blk, 0, stream>>>(C, B, dwt+1080, ST(10), ig+216, ibt+216, ST(11));
  k_pw<72,0><<<BBATCH*HROW, blkpw, 0, stream>>>(B, C, WSLAB(3), ST(11), dg+216, dbt+216, ST(12));
  // out = h1 + relu(BN12(y12))
  k_final<<<2048, blk, 0, stream>>>(C, H, outp, ST(12), pg+216, pbt+216);
  #undef ST
  #undef WSLAB
}